// Round 1
// 191.181 us; speedup vs baseline: 1.0836x; 1.0836x over previous
//
#include <hip/hip_runtime.h>
#include <math.h>

// Problem constants
constexpr int D      = 1024;
constexpr int H      = 16;
constexpr int DH     = 64;
constexpr int Bb     = 2;
constexpr int T      = 2048;
constexpr int BT     = Bb * T;       // 4096
constexpr int CHUNK  = 64;
constexpr int NC     = T / CHUNK;    // 32
constexpr int LS     = 72;           // LDS row stride (shorts) for chunk kernels

typedef __attribute__((ext_vector_type(8))) short bf16x8;
typedef __attribute__((ext_vector_type(4))) float f32x4;

#define GLOAD_LDS16(gp, lp) \
    __builtin_amdgcn_global_load_lds((const __attribute__((address_space(1))) void*)(gp), \
                                     (__attribute__((address_space(3))) void*)(lp), 16, 0, 0)

__device__ __forceinline__ short to_bf16(float f) {
    unsigned u = __float_as_uint(f);
    unsigned r = (u + 0x7fffu + ((u >> 16) & 1u)) >> 16;
    return (short)r;
}
__device__ __forceinline__ float bf2f(short s) {
    return __uint_as_float(((unsigned)(unsigned short)s) << 16);
}

__device__ __forceinline__ float block_sum_256(float v, float* sbuf) {
    #pragma unroll
    for (int off = 32; off > 0; off >>= 1) v += __shfl_down(v, off, 64);
    int lane = threadIdx.x & 63;
    int wid  = threadIdx.x >> 6;
    if (lane == 0) sbuf[wid] = v;
    __syncthreads();
    float r = (threadIdx.x < 4) ? sbuf[threadIdx.x] : 0.0f;
    r += __shfl_down(r, 2, 64);
    r += __shfl_down(r, 1, 64);
    if (threadIdx.x == 0) sbuf[0] = r;
    __syncthreads();
    float outv = sbuf[0];
    __syncthreads();
    return outv;
}

__device__ __forceinline__ float elu1(float x) {
    return x > 0.0f ? x + 1.0f : __expf(x);
}

// ---------------------------------------------------------------------------
// Merged prologue: blocks [0,BT): LayerNorm + zero gmean[row];
// [BT, BT+5120): three weight transposes (fp32 -> bf16, [K,N] -> [N,K]).
// ---------------------------------------------------------------------------
__global__ __launch_bounds__(256) void pre_kernel(const float* __restrict__ x,
                                                  const float* __restrict__ g,
                                                  const float* __restrict__ b,
                                                  const float* __restrict__ wq,
                                                  const float* __restrict__ wg,
                                                  const float* __restrict__ wp,
                                                  short* __restrict__ ynb,
                                                  short* __restrict__ xbb,
                                                  short* __restrict__ wTcomb,
                                                  short* __restrict__ wTp,
                                                  float* __restrict__ gmean) {
    __shared__ float sbuf[4];
    __shared__ short tile[32][33];
    int bid = blockIdx.x;
    if (bid < BT) {
        int row = bid;
        if (threadIdx.x == 0) gmean[row] = 0.0f;
        const float* xr = x + (size_t)row * D;
        int c = threadIdx.x * 4;
        float4 xv = *(const float4*)(xr + c);
        float mu = block_sum_256(xv.x + xv.y + xv.z + xv.w, sbuf) * (1.0f / D);
        float d0 = xv.x - mu, d1 = xv.y - mu, d2 = xv.z - mu, d3 = xv.w - mu;
        float var = block_sum_256(d0*d0 + d1*d1 + d2*d2 + d3*d3, sbuf) * (1.0f / D);
        float rstd = rsqrtf(var + 1e-5f);
        float4 gv = *(const float4*)(g + c);
        float4 bv = *(const float4*)(b + c);
        short4 o, xo;
        o.x = to_bf16(d0 * rstd * gv.x + bv.x);
        o.y = to_bf16(d1 * rstd * gv.y + bv.y);
        o.z = to_bf16(d2 * rstd * gv.z + bv.z);
        o.w = to_bf16(d3 * rstd * gv.w + bv.w);
        xo.x = to_bf16(xv.x); xo.y = to_bf16(xv.y);
        xo.z = to_bf16(xv.z); xo.w = to_bf16(xv.w);
        *(short4*)(ynb + (size_t)row * D + c) = o;
        *(short4*)(xbb + (size_t)row * D + c) = xo;
    } else {
        int t2 = bid - BT;
        const float* W; short* Wt; int N; int t;
        if (t2 < 3072)      { W = wq; Wt = wTcomb;                       N = 3072; t = t2; }
        else if (t2 < 4096) { W = wg; Wt = wTcomb + (size_t)3072 * 1024; N = 1024; t = t2 - 3072; }
        else                { W = wp; Wt = wTp;                          N = 1024; t = t2 - 4096; }
        int ntiles = N >> 5;
        int nb = (t % ntiles) * 32, kb = (t / ntiles) * 32;
        int tx = threadIdx.x & 31, ty = threadIdx.x >> 5;
        #pragma unroll
        for (int i = 0; i < 4; ++i) {
            int k = kb + ty + i * 8;
            tile[ty + i * 8][tx] = to_bf16(W[(size_t)k * N + nb + tx]);
        }
        __syncthreads();
        #pragma unroll
        for (int i = 0; i < 4; ++i) {
            int n = nb + ty + i * 8;
            Wt[(size_t)n * 1024 + kb + tx] = tile[tx][ty + i * 8];
        }
    }
}

// ---------------------------------------------------------------------------
// Combined qkv+gate GEMM, rewritten as the 256^2 / BK=64 / 8-wave counted-vmcnt
// pipeline (T2 swizzle + T3/T4 phases + T5 setprio):
//  - LDS 128 KiB: 2 buffers x { A[kc][256][32], B[kc][256][32] } bf16
//  - 4 phases per K-tile; each phase: ds_read frags | stage one 16KB region
//    (2 x global_load_lds) | s_barrier | lgkmcnt(0) | 16 MFMA (setprio 1) |
//    [counted vmcnt] | s_barrier.  Region lifetimes staggered by k-chunk so
//    the staging target is always one phase dead.  vmcnt never drains to 0
//    in the main loop (10/10 steady; 8/4/0 in the peeled tail).
//  - LDS XOR swizzle: os ^= ((os>>6)&3)<<3 (shorts; selector=row[2:1],
//    modifies 16B slot) applied on reads; staging uses the inverse-swizzled
//    per-lane GLOBAL source with a linear LDS dest (rule #21).
// cols [0,3D): qkv from x_norm; cols [3D,4D): gate from raw x (sigmoid +
// per-row sums via quad shuffle-reduce + atomicAdd into gmean).
// ---------------------------------------------------------------------------
#define SWZ(os) ((os) ^ ((((os) >> 6) & 3) << 3))
#define BARX() __builtin_amdgcn_s_barrier()
#define LGKM0() asm volatile("s_waitcnt lgkmcnt(0)" ::: "memory")
#define VMW(n) asm volatile("s_waitcnt vmcnt(" #n ")" ::: "memory")
#define MEMFENCE() asm volatile("" ::: "memory")

// Stage one 16KB region (matrix half Mp, tile row base rb, K-tile t, k-chunk kc,
// isB selects B side).  Linear LDS dest (wave-uniform base + lane*16), global
// source pre-permuted so that swizzled reads see the right element.
#define STG(Mp, rb, t, kc, isB) do {                                                       \
    short* _b = ldsbuf + ((((t) & 1)) << 15) + (((((isB) << 1) | (kc))) << 13) + wid * 1024; \
    const short* _g = (Mp) + (size_t)((rb) + wid * 32 + s_r) * 1024 + (t) * 64 + (kc) * 32 + s_c; \
    GLOAD_LDS16(_g, _b);                                                                   \
    GLOAD_LDS16(_g + (size_t)16 * 1024, _b + 512);                                         \
} while (0)

#define FRAGA(t, kc, mi) (*(const bf16x8*)(ldsbuf + (((t) & 1) << 15) + ((kc) << 13) + \
    SWZ((wm * 128 + (mi) * 16 + fr) * 32 + fk)))
#define FRAGB(t, kc, ni) (*(const bf16x8*)(ldsbuf + (((t) & 1) << 15) + ((2 + (kc)) << 13) + \
    SWZ((wn * 64 + (ni) * 16 + fr) * 32 + fk)))

// One K-tile group = 4 phases.  S1..S4 gate the staged regions
// (ph1: B1(t+1), ph2: A0(t+2), ph3: B0(t+2), ph4: A1(t+2)); W2/W4 are the
// counted vmcnt waits placed just before the phase-end barrier.
#define GROUP(t, S1, S2, S3, S4, W2, W4) do {                                              \
    bf16x8 af[8], bq[4];                                                                   \
    /* PH1: kc=0, ni 0-1 */                                                                \
    _Pragma("unroll") for (int mi = 0; mi < 8; ++mi) af[mi] = FRAGA(t, 0, mi);             \
    bq[0] = FRAGB(t, 0, 0); bq[1] = FRAGB(t, 0, 1);                                        \
    if (S1) STG(Wt, col0, (t) + 1, 1, 1);                                                  \
    BARX(); LGKM0();                                                                       \
    __builtin_amdgcn_s_setprio(1);                                                         \
    _Pragma("unroll") for (int mi = 0; mi < 8; ++mi) {                                     \
        acc[mi][0] = __builtin_amdgcn_mfma_f32_16x16x32_bf16(af[mi], bq[0], acc[mi][0], 0, 0, 0); \
        acc[mi][1] = __builtin_amdgcn_mfma_f32_16x16x32_bf16(af[mi], bq[1], acc[mi][1], 0, 0, 0); \
    }                                                                                      \
    __builtin_amdgcn_s_setprio(0);                                                         \
    BARX();                                                                                \
    /* PH2: kc=0, ni 2-3 */                                                                \
    bq[2] = FRAGB(t, 0, 2); bq[3] = FRAGB(t, 0, 3);                                        \
    if (S2) STG(Ap, row0, (t) + 2, 0, 0);                                                  \
    BARX(); LGKM0();                                                                       \
    __builtin_amdgcn_s_setprio(1);                                                         \
    _Pragma("unroll") for (int mi = 0; mi < 8; ++mi) {                                     \
        acc[mi][2] = __builtin_amdgcn_mfma_f32_16x16x32_bf16(af[mi], bq[2], acc[mi][2], 0, 0, 0); \
        acc[mi][3] = __builtin_amdgcn_mfma_f32_16x16x32_bf16(af[mi], bq[3], acc[mi][3], 0, 0, 0); \
    }                                                                                      \
    __builtin_amdgcn_s_setprio(0);                                                         \
    W2; BARX();                                                                            \
    /* PH3: kc=1, ni 0-1 */                                                                \
    _Pragma("unroll") for (int mi = 0; mi < 8; ++mi) af[mi] = FRAGA(t, 1, mi);             \
    bq[0] = FRAGB(t, 1, 0); bq[1] = FRAGB(t, 1, 1);                                        \
    if (S3) STG(Wt, col0, (t) + 2, 0, 1);                                                  \
    BARX(); LGKM0();                                                                       \
    __builtin_amdgcn_s_setprio(1);                                                         \
    _Pragma("unroll") for (int mi = 0; mi < 8; ++mi) {                                     \
        acc[mi][0] = __builtin_amdgcn_mfma_f32_16x16x32_bf16(af[mi], bq[0], acc[mi][0], 0, 0, 0); \
        acc[mi][1] = __builtin_amdgcn_mfma_f32_16x16x32_bf16(af[mi], bq[1], acc[mi][1], 0, 0, 0); \
    }                                                                                      \
    __builtin_amdgcn_s_setprio(0);                                                         \
    BARX();                                                                                \
    /* PH4: kc=1, ni 2-3 */                                                                \
    bq[2] = FRAGB(t, 1, 2); bq[3] = FRAGB(t, 1, 3);                                        \
    if (S4) STG(Ap, row0, (t) + 2, 1, 0);                                                  \
    BARX(); LGKM0();                                                                       \
    __builtin_amdgcn_s_setprio(1);                                                         \
    _Pragma("unroll") for (int mi = 0; mi < 8; ++mi) {                                     \
        acc[mi][2] = __builtin_amdgcn_mfma_f32_16x16x32_bf16(af[mi], bq[2], acc[mi][2], 0, 0, 0); \
        acc[mi][3] = __builtin_amdgcn_mfma_f32_16x16x32_bf16(af[mi], bq[3], acc[mi][3], 0, 0, 0); \
    }                                                                                      \
    __builtin_amdgcn_s_setprio(0);                                                         \
    W4; BARX();                                                                            \
} while (0)

__global__ __launch_bounds__(512, 2) void gemm_fused_qkvgate(const short* __restrict__ xnb,
                                                             const short* __restrict__ xb,
                                                             const short* __restrict__ Wt,
                                                             const float* __restrict__ b_qkv,
                                                             const float* __restrict__ b_gate,
                                                             short* __restrict__ qkvb,
                                                             short* __restrict__ sigb,
                                                             float* __restrict__ gmean) {
    // [buf(2)][A kc0 | A kc1 | B kc0 | B kc1] each 8192 shorts -> 128 KiB
    __shared__ short ldsbuf[2 * 32768];

    // XCD-rectangle swizzle over the 16x16 tile grid (bid -> XCD round-robin)
    const int bid   = blockIdx.x;
    const int xcd   = bid & 7;
    const int local = bid >> 3;            // 0..31
    const int cx = xcd & 3, ry = xcd >> 2; // 4 col-slabs x 2 row-slabs
    const int bxx = cx * 4 + (local & 3);  // 0..15 col-block
    const int byy = ry * 8 + (local >> 2); // 0..15 row-block
    const int row0 = byy * 256;
    const int col0 = bxx * 256;
    const bool isg = (col0 >= 3 * D);
    const short* Ap = isg ? xb : xnb;

    const int tid  = threadIdx.x;
    const int wid  = tid >> 6;     // 0..7
    const int lane = tid & 63;
    const int wm = wid >> 2;       // 0..1  (row half)
    const int wn = wid & 3;        // 0..3  (col quarter)
    const int fr = lane & 15;
    const int fk = (lane >> 4) * 8;

    // staging address components (inverse-swizzle of the linear LDS fill)
    const int s_r = lane >> 2;                              // 0..15
    const int s_c = 8 * ((lane & 3) ^ ((lane >> 3) & 3));   // 0,8,16,24 permuted

    f32x4 acc[8][4] = {};

    // Prologue: tile0 {A0,B0,A1,B1} + tile1 {A0,B0,A1}; fences pin issue order
    // so the counted vmcnt bookkeeping holds.
    STG(Ap, row0, 0, 0, 0); MEMFENCE();
    STG(Wt, col0, 0, 0, 1); MEMFENCE();
    STG(Ap, row0, 0, 1, 0); MEMFENCE();
    STG(Wt, col0, 0, 1, 1); MEMFENCE();
    STG(Ap, row0, 1, 0, 0); MEMFENCE();
    STG(Wt, col0, 1, 0, 1); MEMFENCE();
    STG(Ap, row0, 1, 1, 0);
    VMW(10);   // A0(0),B0(0) landed; 10 younger loads still in flight
    BARX();

    for (int t = 0; t < 14; ++t) GROUP(t, 1, 1, 1, 1, VMW(10), VMW(10));
    GROUP(14, 1, 0, 0, 0, VMW(8), VMW(4));
    GROUP(15, 0, 0, 0, 0, VMW(0), (void)0);

    const int ccol  = lane & 15;
    const int crow4 = (lane >> 4) * 4;
    if (!isg) {
        #pragma unroll
        for (int mi = 0; mi < 8; ++mi) {
            #pragma unroll
            for (int ni = 0; ni < 4; ++ni) {
                int col = col0 + wn * 64 + ni * 16 + ccol;
                float bv = b_qkv[col];
                #pragma unroll
                for (int r = 0; r < 4; ++r) {
                    int row = row0 + wm * 128 + mi * 16 + crow4 + r;
                    qkvb[(size_t)row * (3 * D) + col] = to_bf16(acc[mi][ni][r] + bv);
                }
            }
        }
    } else {
        #pragma unroll
        for (int mi = 0; mi < 8; ++mi) {
            #pragma unroll
            for (int r = 0; r < 4; ++r) {
                int lrow = row0 + wm * 128 + mi * 16 + crow4 + r;
                float psum = 0.0f;
                #pragma unroll
                for (int ni = 0; ni < 4; ++ni) {
                    int col = col0 + wn * 64 + ni * 16 + ccol - 3 * D;   // [0,D)
                    float v = acc[mi][ni][r] + b_gate[col];
                    float sv = 1.0f / (1.0f + __expf(-v));
                    sigb[(size_t)lrow * D + col] = to_bf16(sv);
                    psum += sv;
                }
                psum += __shfl_xor(psum, 1, 64);
                psum += __shfl_xor(psum, 2, 64);
                psum += __shfl_xor(psum, 4, 64);
                psum += __shfl_xor(psum, 8, 64);
                if (ccol == 0) atomicAdd(&gmean[lrow], psum);
            }
        }
    }
}

// ---------------------------------------------------------------------------
// Per-chunk state with INLINE gating on k: Sc[m][d] = sum_t Vt[m]*Kg[t][d],
// zc[d] = sum_t Kg[t][d], where Kg = elu1(k * sig/(mean+eps)).
// ---------------------------------------------------------------------------
__global__ __launch_bounds__(256) void chunk_state_mfma(const short* __restrict__ qkvb,
                                                        const short* __restrict__ sigb,
                                                        const float* __restrict__ gmean,
                                                        float* __restrict__ Sc,
                                                        float* __restrict__ zc) {
    __shared__ short Kt[DH * LS];   // [d][t] gated k
    __shared__ short Vt[DH * LS];   // [m][t]
    int idx = blockIdx.x;
    int c = idx & (NC - 1), h = (idx >> 5) & (H - 1), b = idx >> 9;
    size_t bt0 = (size_t)b * T + c * CHUNK;
    const short* kbase = qkvb + bt0 * (3 * D) + D + h * DH;
    const short* vbase = kbase + D;
    const short* sbase = sigb + bt0 * D + h * DH;
    int tid = threadIdx.x;

    #pragma unroll
    for (int l = 0; l < 2; ++l) {
        int i  = tid + l * 256;
        int t  = i >> 3;
        int d8 = (i & 7) * 8;
        float invm = 1.0f / (gmean[bt0 + t] * (1.0f / D) + 1e-5f);
        bf16x8 kv = *(const bf16x8*)(kbase + (size_t)t * (3 * D) + d8);
        bf16x8 vv = *(const bf16x8*)(vbase + (size_t)t * (3 * D) + d8);
        bf16x8 sg = *(const bf16x8*)(sbase + (size_t)t * D + d8);
        #pragma unroll
        for (int j = 0; j < 8; ++j) {
            float gn = bf2f(sg[j]) * invm;
            Kt[(d8 + j) * LS + t] = to_bf16(elu1(bf2f(kv[j]) * gn));
            Vt[(d8 + j) * LS + t] = vv[j];
        }
    }
    __syncthreads();

    const int wv = tid >> 6, lane = tid & 63;
    const int fr = lane & 15, quad = lane >> 4;
    const int fk = quad * 8, crow4 = quad * 4, ccol = lane & 15;
    const int mbase = wv * 16;

    bf16x8 af[2];
    af[0] = *(const bf16x8*)&Vt[(mbase + fr) * LS + fk];
    af[1] = *(const bf16x8*)&Vt[(mbase + fr) * LS + 32 + fk];

    f32x4 acc[4] = {};
    #pragma unroll
    for (int n = 0; n < 4; ++n) {
        #pragma unroll
        for (int ck = 0; ck < 2; ++ck) {
            bf16x8 bk = *(const bf16x8*)&Kt[(n * 16 + fr) * LS + ck * 32 + fk];
            acc[n] = __builtin_amdgcn_mfma_f32_16x16x32_bf16(af[ck], bk, acc[n], 0, 0, 0);
        }
    }

    float* Sd = Sc + (size_t)idx * (DH * DH);
    #pragma unroll
    for (int n = 0; n < 4; ++n)
        #pragma unroll
        for (int r = 0; r < 4; ++r)
            Sd[(mbase + crow4 + r) * DH + n * 16 + ccol] = acc[n][r];

    if (tid < DH) {
        float zs = 0.0f;
        for (int t = 0; t < CHUNK; ++t) zs += bf2f(Kt[tid * LS + t]);
        zc[(size_t)idx * DH + tid] = zs;
    }
}

// ---------------------------------------------------------------------------
// Exclusive prefix over chunks. Reads fp32 Sc, writes bf16 Spb; z in place.
// ---------------------------------------------------------------------------
__global__ __launch_bounds__(256) void chunk_prefix_kernel(const float* __restrict__ S,
                                                           short* __restrict__ Spb,
                                                           float* __restrict__ z) {
    int bh   = blockIdx.x >> 4;
    int part = blockIdx.x & 15;
    int e    = part * 256 + threadIdx.x;
    const float* Sb = S + (size_t)bh * NC * DH * DH;
    short* Pb = Spb + (size_t)bh * NC * DH * DH;
    float acc = 0.0f;
    for (int c = 0; c < NC; ++c) {
        size_t off = (size_t)c * DH * DH + e;
        float t = Sb[off];
        Pb[off] = to_bf16(acc);
        acc += t;
    }
    if (part == 0 && threadIdx.x < DH) {
        float* zb = z + (size_t)bh * NC * DH;
        float za = 0.0f;
        for (int c = 0; c < NC; ++c) {
            float* p = zb + c * DH + threadIdx.x;
            float t = *p; *p = za; za += t;
        }
    }
}

// ---------------------------------------------------------------------------
// Chunk attention with INLINE gating on q,k. As aliases Ks (dead after scores)
// -> LDS ~37 KB -> 4 blocks/CU (was 3). Reads bf16 Sp. Writes bf16 out.
// ---------------------------------------------------------------------------
__global__ __launch_bounds__(256) void chunk_attn_mfma(const short* __restrict__ qkvb,
                                                       const short* __restrict__ sigb,
                                                       const float* __restrict__ gmean,
                                                       const short* __restrict__ Spb,
                                                       const float* __restrict__ zc,
                                                       short* __restrict__ attnb) {
    __shared__ short Qs[CHUNK * LS];   // [t][d] gated q
    __shared__ short Ks[CHUNK * LS];   // [s][d] gated k; reused as As[t][s]
    __shared__ short Vt[DH * LS];      // [m][s]
    __shared__ short Ss[DH * LS];      // [m][d]  (prefix state, bf16)
    __shared__ float zpL[DH];
    __shared__ float den[CHUNK];
    short* As = Ks;                    // alias: Ks dead after scores

    int idx = blockIdx.x;
    int c = idx & (NC - 1), h = (idx >> 5) & (H - 1), b = idx >> 9;
    size_t bt0 = (size_t)b * T + c * CHUNK;
    const short* qbase = qkvb + bt0 * (3 * D) + h * DH;
    const short* kbase = qbase + D;
    const short* vbase = qbase + 2 * D;
    const short* sbase = sigb + bt0 * D + h * DH;
    const short* spb = Spb + (size_t)idx * (DH * DH);
    int tid = threadIdx.x;

    #pragma unroll
    for (int l = 0; l < 2; ++l) {
        int i  = tid + l * 256;
        int t  = i >> 3;
        int d8 = (i & 7) * 8;
        float invm = 1.0f / (gmean[bt0 + t] * (1.0f / D) + 1e-5f);
        bf16x8 qv = *(const bf16x8*)(qbase + (size_t)t * (3 * D) + d8);
        bf16x8 kv = *(const bf16x8*)(kbase + (size_t)t * (3 * D) + d8);
        bf16x8 vv = *(const bf16x8*)(vbase + (size_t)t * (3 * D) + d8);
        bf16x8 sg = *(const bf16x8*)(sbase + (size_t)t * D + d8);
        bf16x8 qg, kg;
        #pragma unroll
        for (int j = 0; j < 8; ++j) {
            float gn = bf2f(sg[j]) * invm;
            qg[j] = to_bf16(elu1(bf2f(qv[j]) * gn));
            kg[j] = to_bf16(elu1(bf2f(kv[j]) * gn));
            Vt[(d8 + j) * LS + t] = vv[j];
        }
        *(bf16x8*)&Qs[t * LS + d8] = qg;
        *(bf16x8*)&Ks[t * LS + d8] = kg;
        *(bf16x8*)&Ss[t * LS + d8] = *(const bf16x8*)(spb + (size_t)i * 8);
    }
    if (tid < DH) zpL[tid] = zc[(size_t)idx * DH + tid];
    __syncthreads();

    const int wv = tid >> 6, lane = tid & 63;
    const int fr = lane & 15, quad = lane >> 4;
    const int fk = quad * 8, crow4 = quad * 4, ccol = lane & 15;
    const int tbase = wv * 16;

    bf16x8 aq[2];
    aq[0] = *(const bf16x8*)&Qs[(tbase + fr) * LS + fk];
    aq[1] = *(const bf16x8*)&Qs[(tbase + fr) * LS + 32 + fk];

    // scores C[t][s] = q_t . k_s
    f32x4 accs[4] = {};
    #pragma unroll
    for (int n = 0; n < 4; ++n) {
        #pragma unroll
        for (int ck = 0; ck < 2; ++ck) {
            bf16x8 bk = *(const bf16x8*)&Ks[(n * 16 + fr) * LS + ck * 32 + fk];
            accs[n] = __builtin_amdgcn_mfma_f32_16x16x32_bf16(aq[ck], bk, accs[n], 0, 0, 0);
        }
    }
    __syncthreads();   // all Ks reads complete before As overwrites it

    float part[4] = {0.f, 0.f, 0.f, 0.f};
    #pragma unroll
    for (int n = 0; n < 4; ++n) {
        #pragma unroll
        for (int r = 0; r < 4; ++r) {
            int tt = tbase + crow4 + r;
            int ss = n * 16 + ccol;
            float v = (ss <= tt) ? accs[n][r] : 0.0f;
            part[r] += v;
            As[tt * LS + ss] = to_bf16(v);
        }
    }
    #pragma unroll
    for (int r = 0; r < 4; ++r) {
        part[r] += __shfl_xor(part[r], 1, 64);
        part[r] += __shfl_xor(part[r], 2, 64);
        part[r] += __shfl_xor(part[r], 4, 64);
        part[r] += __shfl_xor(part[r], 8, 64);
    }
    if (fr == 0) {
        #pragma unroll
        for (int r = 0; r < 4; ++r) den[tbase + crow4 + r] = part[r];
    }
    __syncthreads();

    if (tid < CHUNK) {
        float qz = 0.0f;
        #pragma unroll 8
        for (int d = 0; d < DH; ++d) qz += bf2f(Qs[tid * LS + d]) * zpL[d];
        den[tid] += qz + 1e-5f;
    }

    // out C[t][m] = Q @ Sp + A @ V
    f32x4 acco[4] = {};
    #pragma unroll
    for (int m4 = 0; m4 < 4; ++m4) {
        #pragma unroll
        for (int ck = 0; ck < 2; ++ck) {
            bf16x8 bs = *(const bf16x8*)&Ss[(m4 * 16 + fr) * LS + ck * 32 + fk];
            acco[m4] = __builtin_amdgcn_mfma_f32_16x16x32_bf16(aq[ck], bs, acco[m4], 0, 0, 0);
        }
    }
    bf16x8 aa[2];
    aa[0] = *(const bf16x8*)&As[(tbase + fr) * LS + fk];
    aa[1] = *(const bf16x8*)&As[(tbase + fr) * LS + 32 + fk];
    #pragma unroll
    for (int m4 = 0; m4 < 4; ++m4) {
        #pragma unroll
        for (int ck = 0; ck < 2; ++ck) {
            bf16x8 bv = *(const bf16x8*)&Vt[(m4 * 16 + fr) * LS + ck * 32 + fk];
            acco[m4] = __builtin_amdgcn_mfma_f32_16x16x32_bf16(aa[ck], bv, acco[m4], 0, 0, 0);
        }
    }
    __syncthreads();

    short* obase = attnb + bt0 * D + h * DH;
    #pragma unroll
    for (int r = 0; r < 4; ++r) {
        int tt = tbase + crow4 + r;
        float rv = 1.0f / den[tt];
        #pragma unroll
        for (int m4 = 0; m4 < 4; ++m4)
            obase[(size_t)tt * D + m4 * 16 + ccol] = to_bf16(acco[m4][r] * rv);
    }
}

// ---------------------------------------------------------------------------
// Proj GEMM, BK=32 + XCD-rectangle swizzle (2-col x 32-row rectangles).
// C[4096][1024] fp32 = A @ Bt^T + bias. 64x128 tile, 1D grid 512.
// ---------------------------------------------------------------------------
__global__ __launch_bounds__(256) void gemm_proj64(const short* __restrict__ A,
                                                   const short* __restrict__ Bt,
                                                   const float* __restrict__ bias,
                                                   float* __restrict__ C) {
    constexpr int BK = 32, K = 1024, N = 1024;
    __shared__ short Als[64 * BK];    // 4 KB
    __shared__ short Bls[128 * BK];   // 8 KB

    const int bid   = blockIdx.x;
    const int xcd   = bid & 7;
    const int local = bid >> 3;            // 0..63
    const int cx = xcd & 3, ry = xcd >> 2; // 4 col-slabs x 2 row-slabs
    const int lx = local & 1, ly = local >> 1;
    const int bxx = cx * 2 + lx;           // 0..7 col-block
    const int byy = ry * 32 + ly;          // 0..63 row-block

    const int tid  = threadIdx.x;
    const int wave = tid >> 6;
    const int lane = tid & 63;
    const int row0 = byy * 64;
    const int col0 = bxx * 128;
    const int wn = wave * 32;

    f32x4 acc[4][2] = {};
    const int srow = lane >> 2;
    const int skk  = (lane & 3) * 8;
    const int fr = lane & 15;
    const int fk = (lane >> 4) * 8;

    for (int k0 = 0; k0 < K; k0 += BK) {
        __syncthreads();
        #pragma unroll
        for (int u = 0; u < 3; ++u) {
            int cc = wave * 3 + u;   // 0..11; 0..3 -> A chunks, 4..11 -> B chunks
            if (cc < 4) {
                int r = cc * 16 + srow;
                GLOAD_LDS16(A + (size_t)(row0 + r) * K + k0 + skk, &Als[cc * 512]);
            } else {
                int c2 = cc - 4;
                int r = c2 * 16 + srow;
                GLOAD_LDS16(Bt + (size_t)(col0 + r) * K + k0 + skk, &Bls[c2 * 512]);
            }
        }
        __syncthreads();

        bf16x8 af[4], bfr[2];
        #pragma unroll
        for (int i = 0; i < 4; ++i)
            af[i] = *(const bf16x8*)&Als[(i * 16 + fr) * BK + fk];
        #pragma unroll
        for (int j = 0; j < 2; ++j)
            bfr[j] = *(const bf16x8*)&Bls[(wn + j * 16 + fr) * BK + fk];
        #pragma unroll
        for (int mi = 0; mi < 4; ++mi)
            #pragma unroll
            for (int ni = 0; ni < 2; ++ni)
                acc[mi][ni] = __builtin_amdgcn_mfma_f32_16x16x32_bf16(af[mi], bfr[ni], acc[mi][ni], 0, 0, 0);
    }

    const int ccol  = lane & 15;
    const int crow4 = (lane >> 4) * 4;
    #pragma unroll
    for (int mi = 0; mi < 4; ++mi) {
        #pragma unroll
        for (int ni = 0; ni < 2; ++ni) {
            int col = col0 + wn + ni * 16 + ccol;
            float bv = bias[col];
            #pragma unroll
            for (int r = 0; r < 4; ++r) {
                int row = row0 + mi * 16 + crow4 + r;
                C[(size_t)row * N + col] = acc[mi][ni][r] + bv;
            }
        }
    }
}

// ---------------------------------------------------------------------------
extern "C" void kernel_launch(void* const* d_in, const int* in_sizes, int n_in,
                              void* d_out, int out_size, void* d_ws, size_t ws_size,
                              hipStream_t stream) {
    const float* x      = (const float*)d_in[0];
    const float* ln_g   = (const float*)d_in[1];
    const float* ln_b   = (const float*)d_in[2];
    const float* w_qkv  = (const float*)d_in[3];
    const float* b_qkv  = (const float*)d_in[4];
    const float* w_gate = (const float*)d_in[5];
    const float* b_gate = (const float*)d_in[6];
    const float* w_proj = (const float*)d_in[7];
    const float* b_proj = (const float*)d_in[8];
    float* out = (float*)d_out;

    short* xnb   = (short*)d_ws;                       // BT*D bf16 (8 MB)  [dead after GEMM]
    short* xb    = xnb + (size_t)BT * D;               // BT*D bf16 (8 MB)  [dead after GEMM]
    short* wTc   = xb + (size_t)BT * D;                // 4096*1024 bf16 (8 MB) [dead after GEMM]
    short* wTp   = wTc + (size_t)4096 * 1024;          // D*D bf16 (2 MB)
    short* qkvb  = wTp + (size_t)D * D;                // BT*3D bf16 (24 MB)
    short* sigb  = qkvb + (size_t)BT * 3 * D;          // BT*D bf16 (8 MB)
    short* attnb = sigb + (size_t)BT * D;              // BT*D bf16 (8 MB)
    float* zc    = (float*)(attnb + (size_t)BT * D);   // Bb*H*NC*DH fp32 (256 KB)
    float* gmean = zc + (size_t)Bb * H * NC * DH;      // BT fp32 (16 KB)
    float* Sc    = (float*)xnb;                        // Bb*H*NC*DH*DH fp32 (16 MB), aliases xnb+xb
    short* Spb   = wTc;                                // BT*D bf16 (8 MB), aliases wTc

    pre_kernel<<<BT + 5120, 256, 0, stream>>>(x, ln_g, ln_b, w_qkv, w_gate, w_proj,
                                              xnb, xb, wTc, wTp, gmean);
    gemm_fused_qkvgate<<<256, 512, 0, stream>>>(
        xnb, xb, wTc, b_qkv, b_gate, qkvb, sigb, gmean);
    chunk_state_mfma<<<Bb * H * NC, 256, 0, stream>>>(qkvb, sigb, gmean, Sc, zc);
    chunk_prefix_kernel<<<Bb * H * 16, 256, 0, stream>>>(Sc, Spb, zc);
    chunk_attn_mfma<<<Bb * H * NC, 256, 0, stream>>>(qkvb, sigb, gmean, Spb, zc, attnb);
    gemm_proj64<<<512, 256, 0, stream>>>(attnb, wTp, b_proj, out);
}

// Round 3
// 190.578 us; speedup vs baseline: 1.0870x; 1.0032x over previous
//
#include <hip/hip_runtime.h>
#include <math.h>

// Problem constants
constexpr int D      = 1024;
constexpr int H      = 16;
constexpr int DH     = 64;
constexpr int Bb     = 2;
constexpr int T      = 2048;
constexpr int BT     = Bb * T;       // 4096
constexpr int CHUNK  = 64;
constexpr int NC     = T / CHUNK;    // 32
constexpr int LS     = 72;           // LDS row stride (shorts) for chunk kernels

typedef __attribute__((ext_vector_type(8))) short bf16x8;
typedef __attribute__((ext_vector_type(4))) float f32x4;

#define GLOAD_LDS16(gp, lp) \
    __builtin_amdgcn_global_load_lds((const __attribute__((address_space(1))) void*)(gp), \
                                     (__attribute__((address_space(3))) void*)(lp), 16, 0, 0)

__device__ __forceinline__ short to_bf16(float f) {
    unsigned u = __float_as_uint(f);
    unsigned r = (u + 0x7fffu + ((u >> 16) & 1u)) >> 16;
    return (short)r;
}
__device__ __forceinline__ float bf2f(short s) {
    return __uint_as_float(((unsigned)(unsigned short)s) << 16);
}

__device__ __forceinline__ float elu1(float x) {
    return x > 0.0f ? x + 1.0f : __expf(x);
}

// ---------------------------------------------------------------------------
// Merged prologue: blocks [0,1024): LayerNorm, 4 rows/block, one wave per row
// (in-register shfl_xor butterfly reductions, no barriers) + zero gmean[row];
// [1024, 1024+5120): three weight transposes (fp32 -> bf16, [K,N] -> [N,K]).
// NOTE: no cooperative launches anywhere — harness graph-captures the stream,
// and hipLaunchCooperativeKernel is not capturable (R2 failure).
// ---------------------------------------------------------------------------
__global__ __launch_bounds__(256) void pre_kernel(const float* __restrict__ x,
                                                  const float* __restrict__ g,
                                                  const float* __restrict__ b,
                                                  const float* __restrict__ wq,
                                                  const float* __restrict__ wg,
                                                  const float* __restrict__ wp,
                                                  short* __restrict__ ynb,
                                                  short* __restrict__ xbb,
                                                  short* __restrict__ wTcomb,
                                                  short* __restrict__ wTp,
                                                  float* __restrict__ gmean) {
    __shared__ short tile[32][33];
    int bid = blockIdx.x;
    if (bid < 1024) {
        int row  = bid * 4 + (threadIdx.x >> 6);
        int lane = threadIdx.x & 63;
        const float* xr = x + (size_t)row * D;
        float4 xv[4];
        float s = 0.0f;
        #pragma unroll
        for (int i = 0; i < 4; ++i) {
            xv[i] = *(const float4*)(xr + i * 256 + lane * 4);
            s += xv[i].x + xv[i].y + xv[i].z + xv[i].w;
        }
        #pragma unroll
        for (int off = 32; off > 0; off >>= 1) s += __shfl_xor(s, off, 64);
        float mu = s * (1.0f / D);
        float vs = 0.0f;
        #pragma unroll
        for (int i = 0; i < 4; ++i) {
            float d0 = xv[i].x - mu, d1 = xv[i].y - mu;
            float d2 = xv[i].z - mu, d3 = xv[i].w - mu;
            vs += d0 * d0 + d1 * d1 + d2 * d2 + d3 * d3;
        }
        #pragma unroll
        for (int off = 32; off > 0; off >>= 1) vs += __shfl_xor(vs, off, 64);
        float rstd = rsqrtf(vs * (1.0f / D) + 1e-5f);
        if (lane == 0) gmean[row] = 0.0f;
        #pragma unroll
        for (int i = 0; i < 4; ++i) {
            int cc = i * 256 + lane * 4;
            float4 gv = *(const float4*)(g + cc);
            float4 bv = *(const float4*)(b + cc);
            short4 o, xo;
            o.x = to_bf16((xv[i].x - mu) * rstd * gv.x + bv.x);
            o.y = to_bf16((xv[i].y - mu) * rstd * gv.y + bv.y);
            o.z = to_bf16((xv[i].z - mu) * rstd * gv.z + bv.z);
            o.w = to_bf16((xv[i].w - mu) * rstd * gv.w + bv.w);
            xo.x = to_bf16(xv[i].x); xo.y = to_bf16(xv[i].y);
            xo.z = to_bf16(xv[i].z); xo.w = to_bf16(xv[i].w);
            *(short4*)(ynb + (size_t)row * D + cc) = o;
            *(short4*)(xbb + (size_t)row * D + cc) = xo;
        }
    } else {
        int t2 = bid - 1024;
        const float* W; short* Wt; int N; int t;
        if (t2 < 3072)      { W = wq; Wt = wTcomb;                       N = 3072; t = t2; }
        else if (t2 < 4096) { W = wg; Wt = wTcomb + (size_t)3072 * 1024; N = 1024; t = t2 - 3072; }
        else                { W = wp; Wt = wTp;                          N = 1024; t = t2 - 4096; }
        int ntiles = N >> 5;
        int nb = (t % ntiles) * 32, kb = (t / ntiles) * 32;
        int tx = threadIdx.x & 31, ty = threadIdx.x >> 5;
        #pragma unroll
        for (int i = 0; i < 4; ++i) {
            int k = kb + ty + i * 8;
            tile[ty + i * 8][tx] = to_bf16(W[(size_t)k * N + nb + tx]);
        }
        __syncthreads();
        #pragma unroll
        for (int i = 0; i < 4; ++i) {
            int n = nb + ty + i * 8;
            Wt[(size_t)n * 1024 + kb + tx] = tile[tx][ty + i * 8];
        }
    }
}

// ---------------------------------------------------------------------------
// Combined qkv+gate GEMM: 256^2 / BK=64 / 8-wave counted-vmcnt pipeline
// (unchanged from R1: 50.0 us, 0 bank conflicts).
// ---------------------------------------------------------------------------
#define SWZ(os) ((os) ^ ((((os) >> 6) & 3) << 3))
#define BARX() __builtin_amdgcn_s_barrier()
#define LGKM0() asm volatile("s_waitcnt lgkmcnt(0)" ::: "memory")
#define VMW(n) asm volatile("s_waitcnt vmcnt(" #n ")" ::: "memory")
#define MEMFENCE() asm volatile("" ::: "memory")

#define STG(Mp, rb, t, kc, isB) do {                                                       \
    short* _b = ldsbuf + ((((t) & 1)) << 15) + (((((isB) << 1) | (kc))) << 13) + wid * 1024; \
    const short* _g = (Mp) + (size_t)((rb) + wid * 32 + s_r) * 1024 + (t) * 64 + (kc) * 32 + s_c; \
    GLOAD_LDS16(_g, _b);                                                                   \
    GLOAD_LDS16(_g + (size_t)16 * 1024, _b + 512);                                         \
} while (0)

#define FRAGA(t, kc, mi) (*(const bf16x8*)(ldsbuf + (((t) & 1) << 15) + ((kc) << 13) + \
    SWZ((wm * 128 + (mi) * 16 + fr) * 32 + fk)))
#define FRAGB(t, kc, ni) (*(const bf16x8*)(ldsbuf + (((t) & 1) << 15) + ((2 + (kc)) << 13) + \
    SWZ((wn * 64 + (ni) * 16 + fr) * 32 + fk)))

#define GROUP(t, S1, S2, S3, S4, W2, W4) do {                                              \
    bf16x8 af[8], bq[4];                                                                   \
    _Pragma("unroll") for (int mi = 0; mi < 8; ++mi) af[mi] = FRAGA(t, 0, mi);             \
    bq[0] = FRAGB(t, 0, 0); bq[1] = FRAGB(t, 0, 1);                                        \
    if (S1) STG(Wt, col0, (t) + 1, 1, 1);                                                  \
    BARX(); LGKM0();                                                                       \
    __builtin_amdgcn_s_setprio(1);                                                         \
    _Pragma("unroll") for (int mi = 0; mi < 8; ++mi) {                                     \
        acc[mi][0] = __builtin_amdgcn_mfma_f32_16x16x32_bf16(af[mi], bq[0], acc[mi][0], 0, 0, 0); \
        acc[mi][1] = __builtin_amdgcn_mfma_f32_16x16x32_bf16(af[mi], bq[1], acc[mi][1], 0, 0, 0); \
    }                                                                                      \
    __builtin_amdgcn_s_setprio(0);                                                         \
    BARX();                                                                                \
    bq[2] = FRAGB(t, 0, 2); bq[3] = FRAGB(t, 0, 3);                                        \
    if (S2) STG(Ap, row0, (t) + 2, 0, 0);                                                  \
    BARX(); LGKM0();                                                                       \
    __builtin_amdgcn_s_setprio(1);                                                         \
    _Pragma("unroll") for (int mi = 0; mi < 8; ++mi) {                                     \
        acc[mi][2] = __builtin_amdgcn_mfma_f32_16x16x32_bf16(af[mi], bq[2], acc[mi][2], 0, 0, 0); \
        acc[mi][3] = __builtin_amdgcn_mfma_f32_16x16x32_bf16(af[mi], bq[3], acc[mi][3], 0, 0, 0); \
    }                                                                                      \
    __builtin_amdgcn_s_setprio(0);                                                         \
    W2; BARX();                                                                            \
    _Pragma("unroll") for (int mi = 0; mi < 8; ++mi) af[mi] = FRAGA(t, 1, mi);             \
    bq[0] = FRAGB(t, 1, 0); bq[1] = FRAGB(t, 1, 1);                                        \
    if (S3) STG(Wt, col0, (t) + 2, 0, 1);                                                  \
    BARX(); LGKM0();                                                                       \
    __builtin_amdgcn_s_setprio(1);                                                         \
    _Pragma("unroll") for (int mi = 0; mi < 8; ++mi) {                                     \
        acc[mi][0] = __builtin_amdgcn_mfma_f32_16x16x32_bf16(af[mi], bq[0], acc[mi][0], 0, 0, 0); \
        acc[mi][1] = __builtin_amdgcn_mfma_f32_16x16x32_bf16(af[mi], bq[1], acc[mi][1], 0, 0, 0); \
    }                                                                                      \
    __builtin_amdgcn_s_setprio(0);                                                         \
    BARX();                                                                                \
    bq[2] = FRAGB(t, 1, 2); bq[3] = FRAGB(t, 1, 3);                                        \
    if (S4) STG(Ap, row0, (t) + 2, 1, 0);                                                  \
    BARX(); LGKM0();                                                                       \
    __builtin_amdgcn_s_setprio(1);                                                         \
    _Pragma("unroll") for (int mi = 0; mi < 8; ++mi) {                                     \
        acc[mi][2] = __builtin_amdgcn_mfma_f32_16x16x32_bf16(af[mi], bq[2], acc[mi][2], 0, 0, 0); \
        acc[mi][3] = __builtin_amdgcn_mfma_f32_16x16x32_bf16(af[mi], bq[3], acc[mi][3], 0, 0, 0); \
    }                                                                                      \
    __builtin_amdgcn_s_setprio(0);                                                         \
    W4; BARX();                                                                            \
} while (0)

__global__ __launch_bounds__(512, 2) void gemm_fused_qkvgate(const short* __restrict__ xnb,
                                                             const short* __restrict__ xb,
                                                             const short* __restrict__ Wt,
                                                             const float* __restrict__ b_qkv,
                                                             const float* __restrict__ b_gate,
                                                             short* __restrict__ qkvb,
                                                             short* __restrict__ sigb,
                                                             float* __restrict__ gmean) {
    __shared__ short ldsbuf[2 * 32768];

    const int bid   = blockIdx.x;
    const int xcd   = bid & 7;
    const int local = bid >> 3;            // 0..31
    const int cx = xcd & 3, ry = xcd >> 2; // 4 col-slabs x 2 row-slabs
    const int bxx = cx * 4 + (local & 3);  // 0..15 col-block
    const int byy = ry * 8 + (local >> 2); // 0..15 row-block
    const int row0 = byy * 256;
    const int col0 = bxx * 256;
    const bool isg = (col0 >= 3 * D);
    const short* Ap = isg ? xb : xnb;

    const int tid  = threadIdx.x;
    const int wid  = tid >> 6;     // 0..7
    const int lane = tid & 63;
    const int wm = wid >> 2;       // 0..1  (row half)
    const int wn = wid & 3;        // 0..3  (col quarter)
    const int fr = lane & 15;
    const int fk = (lane >> 4) * 8;

    const int s_r = lane >> 2;                              // 0..15
    const int s_c = 8 * ((lane & 3) ^ ((lane >> 3) & 3));   // 0,8,16,24 permuted

    f32x4 acc[8][4] = {};

    STG(Ap, row0, 0, 0, 0); MEMFENCE();
    STG(Wt, col0, 0, 0, 1); MEMFENCE();
    STG(Ap, row0, 0, 1, 0); MEMFENCE();
    STG(Wt, col0, 0, 1, 1); MEMFENCE();
    STG(Ap, row0, 1, 0, 0); MEMFENCE();
    STG(Wt, col0, 1, 0, 1); MEMFENCE();
    STG(Ap, row0, 1, 1, 0);
    VMW(10);
    BARX();

    for (int t = 0; t < 14; ++t) GROUP(t, 1, 1, 1, 1, VMW(10), VMW(10));
    GROUP(14, 1, 0, 0, 0, VMW(8), VMW(4));
    GROUP(15, 0, 0, 0, 0, VMW(0), (void)0);

    const int ccol  = lane & 15;
    const int crow4 = (lane >> 4) * 4;
    if (!isg) {
        #pragma unroll
        for (int mi = 0; mi < 8; ++mi) {
            #pragma unroll
            for (int ni = 0; ni < 4; ++ni) {
                int col = col0 + wn * 64 + ni * 16 + ccol;
                float bv = b_qkv[col];
                #pragma unroll
                for (int r = 0; r < 4; ++r) {
                    int row = row0 + wm * 128 + mi * 16 + crow4 + r;
                    qkvb[(size_t)row * (3 * D) + col] = to_bf16(acc[mi][ni][r] + bv);
                }
            }
        }
    } else {
        #pragma unroll
        for (int mi = 0; mi < 8; ++mi) {
            #pragma unroll
            for (int r = 0; r < 4; ++r) {
                int lrow = row0 + wm * 128 + mi * 16 + crow4 + r;
                float psum = 0.0f;
                #pragma unroll
                for (int ni = 0; ni < 4; ++ni) {
                    int col = col0 + wn * 64 + ni * 16 + ccol - 3 * D;   // [0,D)
                    float v = acc[mi][ni][r] + b_gate[col];
                    float sv = 1.0f / (1.0f + __expf(-v));
                    sigb[(size_t)lrow * D + col] = to_bf16(sv);
                    psum += sv;
                }
                psum += __shfl_xor(psum, 1, 64);
                psum += __shfl_xor(psum, 2, 64);
                psum += __shfl_xor(psum, 4, 64);
                psum += __shfl_xor(psum, 8, 64);
                if (ccol == 0) atomicAdd(&gmean[lrow], psum);
            }
        }
    }
}

// ---------------------------------------------------------------------------
// Per-chunk state with INLINE gating on k: Sc[m][d] = sum_t Vt[m]*Kg[t][d],
// zc[d] = sum_t Kg[t][d].  z-sum parallelized across all 256 threads
// (d = tid>>2, 16-wide t-slice per lane, 2-step shfl_xor combine).
// ---------------------------------------------------------------------------
__global__ __launch_bounds__(256) void chunk_state_mfma(const short* __restrict__ qkvb,
                                                        const short* __restrict__ sigb,
                                                        const float* __restrict__ gmean,
                                                        float* __restrict__ Sc,
                                                        float* __restrict__ zc) {
    __shared__ short Kt[DH * LS];   // [d][t] gated k
    __shared__ short Vt[DH * LS];   // [m][t]
    int idx = blockIdx.x;
    int c = idx & (NC - 1), h = (idx >> 5) & (H - 1), b = idx >> 9;
    size_t bt0 = (size_t)b * T + c * CHUNK;
    const short* kbase = qkvb + bt0 * (3 * D) + D + h * DH;
    const short* vbase = kbase + D;
    const short* sbase = sigb + bt0 * D + h * DH;
    int tid = threadIdx.x;

    #pragma unroll
    for (int l = 0; l < 2; ++l) {
        int i  = tid + l * 256;
        int t  = i >> 3;
        int d8 = (i & 7) * 8;
        float invm = 1.0f / (gmean[bt0 + t] * (1.0f / D) + 1e-5f);
        bf16x8 kv = *(const bf16x8*)(kbase + (size_t)t * (3 * D) + d8);
        bf16x8 vv = *(const bf16x8*)(vbase + (size_t)t * (3 * D) + d8);
        bf16x8 sg = *(const bf16x8*)(sbase + (size_t)t * D + d8);
        #pragma unroll
        for (int j = 0; j < 8; ++j) {
            float gn = bf2f(sg[j]) * invm;
            Kt[(d8 + j) * LS + t] = to_bf16(elu1(bf2f(kv[j]) * gn));
            Vt[(d8 + j) * LS + t] = vv[j];
        }
    }
    __syncthreads();

    const int wv = tid >> 6, lane = tid & 63;
    const int fr = lane & 15, quad = lane >> 4;
    const int fk = quad * 8, crow4 = quad * 4, ccol = lane & 15;
    const int mbase = wv * 16;

    bf16x8 af[2];
    af[0] = *(const bf16x8*)&Vt[(mbase + fr) * LS + fk];
    af[1] = *(const bf16x8*)&Vt[(mbase + fr) * LS + 32 + fk];

    f32x4 acc[4] = {};
    #pragma unroll
    for (int n = 0; n < 4; ++n) {
        #pragma unroll
        for (int ck = 0; ck < 2; ++ck) {
            bf16x8 bk = *(const bf16x8*)&Kt[(n * 16 + fr) * LS + ck * 32 + fk];
            acc[n] = __builtin_amdgcn_mfma_f32_16x16x32_bf16(af[ck], bk, acc[n], 0, 0, 0);
        }
    }

    float* Sd = Sc + (size_t)idx * (DH * DH);
    #pragma unroll
    for (int n = 0; n < 4; ++n)
        #pragma unroll
        for (int r = 0; r < 4; ++r)
            Sd[(mbase + crow4 + r) * DH + n * 16 + ccol] = acc[n][r];

    // zc[d] = sum_t Kt[d][t], all threads: d = tid>>2, t-slice = (tid&3)*16..+16
    {
        int d = tid >> 2, p = tid & 3;
        bf16x8 k0 = *(const bf16x8*)&Kt[d * LS + p * 16];
        bf16x8 k1 = *(const bf16x8*)&Kt[d * LS + p * 16 + 8];
        float zs = 0.0f;
        #pragma unroll
        for (int j = 0; j < 8; ++j) zs += bf2f(k0[j]) + bf2f(k1[j]);
        zs += __shfl_xor(zs, 1, 64);
        zs += __shfl_xor(zs, 2, 64);
        if (p == 0) zc[(size_t)idx * DH + d] = zs;
    }
}

// ---------------------------------------------------------------------------
// Exclusive prefix over chunks, register-pipelined (load all 32, then scan).
// Reads fp32 Sc, writes bf16 Spb; z in place.
// ---------------------------------------------------------------------------
__global__ __launch_bounds__(256) void chunk_prefix_kernel(const float* __restrict__ S,
                                                           short* __restrict__ Spb,
                                                           float* __restrict__ z) {
    int bh   = blockIdx.x >> 4;
    int part = blockIdx.x & 15;
    int e    = part * 256 + threadIdx.x;
    const float* Sb = S + (size_t)bh * NC * DH * DH;
    short* Pb = Spb + (size_t)bh * NC * DH * DH;
    float v[NC];
    #pragma unroll
    for (int c = 0; c < NC; ++c) v[c] = Sb[(size_t)c * DH * DH + e];
    float acc = 0.0f;
    #pragma unroll
    for (int c = 0; c < NC; ++c) {
        Pb[(size_t)c * DH * DH + e] = to_bf16(acc);
        acc += v[c];
    }
    if (part == 0 && threadIdx.x < DH) {
        float* zb = z + (size_t)bh * NC * DH + threadIdx.x;
        float zv[NC];
        #pragma unroll
        for (int c = 0; c < NC; ++c) zv[c] = zb[(size_t)c * DH];
        float za = 0.0f;
        #pragma unroll
        for (int c = 0; c < NC; ++c) {
            zb[(size_t)c * DH] = za;
            za += zv[c];
        }
    }
}

// ---------------------------------------------------------------------------
// Chunk attention with INLINE gating on q,k. As aliases Ks (dead after scores).
// q.z denominator term parallelized across all 256 threads.
// ---------------------------------------------------------------------------
__global__ __launch_bounds__(256) void chunk_attn_mfma(const short* __restrict__ qkvb,
                                                       const short* __restrict__ sigb,
                                                       const float* __restrict__ gmean,
                                                       const short* __restrict__ Spb,
                                                       const float* __restrict__ zc,
                                                       short* __restrict__ attnb) {
    __shared__ short Qs[CHUNK * LS];   // [t][d] gated q
    __shared__ short Ks[CHUNK * LS];   // [s][d] gated k; reused as As[t][s]
    __shared__ short Vt[DH * LS];      // [m][s]
    __shared__ short Ss[DH * LS];      // [m][d]  (prefix state, bf16)
    __shared__ float zpL[DH];
    __shared__ float den[CHUNK];
    short* As = Ks;                    // alias: Ks dead after scores

    int idx = blockIdx.x;
    int c = idx & (NC - 1), h = (idx >> 5) & (H - 1), b = idx >> 9;
    size_t bt0 = (size_t)b * T + c * CHUNK;
    const short* qbase = qkvb + bt0 * (3 * D) + h * DH;
    const short* kbase = qbase + D;
    const short* vbase = qbase + 2 * D;
    const short* sbase = sigb + bt0 * D + h * DH;
    const short* spb = Spb + (size_t)idx * (DH * DH);
    int tid = threadIdx.x;

    #pragma unroll
    for (int l = 0; l < 2; ++l) {
        int i  = tid + l * 256;
        int t  = i >> 3;
        int d8 = (i & 7) * 8;
        float invm = 1.0f / (gmean[bt0 + t] * (1.0f / D) + 1e-5f);
        bf16x8 qv = *(const bf16x8*)(qbase + (size_t)t * (3 * D) + d8);
        bf16x8 kv = *(const bf16x8*)(kbase + (size_t)t * (3 * D) + d8);
        bf16x8 vv = *(const bf16x8*)(vbase + (size_t)t * (3 * D) + d8);
        bf16x8 sg = *(const bf16x8*)(sbase + (size_t)t * D + d8);
        bf16x8 qg, kg;
        #pragma unroll
        for (int j = 0; j < 8; ++j) {
            float gn = bf2f(sg[j]) * invm;
            qg[j] = to_bf16(elu1(bf2f(qv[j]) * gn));
            kg[j] = to_bf16(elu1(bf2f(kv[j]) * gn));
            Vt[(d8 + j) * LS + t] = vv[j];
        }
        *(bf16x8*)&Qs[t * LS + d8] = qg;
        *(bf16x8*)&Ks[t * LS + d8] = kg;
        *(bf16x8*)&Ss[t * LS + d8] = *(const bf16x8*)(spb + (size_t)i * 8);
    }
    if (tid < DH) zpL[tid] = zc[(size_t)idx * DH + tid];
    __syncthreads();

    const int wv = tid >> 6, lane = tid & 63;
    const int fr = lane & 15, quad = lane >> 4;
    const int fk = quad * 8, crow4 = quad * 4, ccol = lane & 15;
    const int tbase = wv * 16;

    bf16x8 aq[2];
    aq[0] = *(const bf16x8*)&Qs[(tbase + fr) * LS + fk];
    aq[1] = *(const bf16x8*)&Qs[(tbase + fr) * LS + 32 + fk];

    // scores C[t][s] = q_t . k_s
    f32x4 accs[4] = {};
    #pragma unroll
    for (int n = 0; n < 4; ++n) {
        #pragma unroll
        for (int ck = 0; ck < 2; ++ck) {
            bf16x8 bk = *(const bf16x8*)&Ks[(n * 16 + fr) * LS + ck * 32 + fk];
            accs[n] = __builtin_amdgcn_mfma_f32_16x16x32_bf16(aq[ck], bk, accs[n], 0, 0, 0);
        }
    }
    __syncthreads();   // all Ks reads complete before As overwrites it

    float part[4] = {0.f, 0.f, 0.f, 0.f};
    #pragma unroll
    for (int n = 0; n < 4; ++n) {
        #pragma unroll
        for (int r = 0; r < 4; ++r) {
            int tt = tbase + crow4 + r;
            int ss = n * 16 + ccol;
            float v = (ss <= tt) ? accs[n][r] : 0.0f;
            part[r] += v;
            As[tt * LS + ss] = to_bf16(v);
        }
    }
    #pragma unroll
    for (int r = 0; r < 4; ++r) {
        part[r] += __shfl_xor(part[r], 1, 64);
        part[r] += __shfl_xor(part[r], 2, 64);
        part[r] += __shfl_xor(part[r], 4, 64);
        part[r] += __shfl_xor(part[r], 8, 64);
    }
    if (fr == 0) {
        #pragma unroll
        for (int r = 0; r < 4; ++r) den[tbase + crow4 + r] = part[r];
    }
    __syncthreads();

    // den[t] += q_t . zp, all threads: t = tid>>2, d-slice = (tid&3)*16..+16
    {
        int t = tid >> 2, p = tid & 3;
        bf16x8 q0 = *(const bf16x8*)&Qs[t * LS + p * 16];
        bf16x8 q1 = *(const bf16x8*)&Qs[t * LS + p * 16 + 8];
        float qz = 0.0f;
        #pragma unroll
        for (int j = 0; j < 8; ++j)
            qz += bf2f(q0[j]) * zpL[p * 16 + j] + bf2f(q1[j]) * zpL[p * 16 + 8 + j];
        qz += __shfl_xor(qz, 1, 64);
        qz += __shfl_xor(qz, 2, 64);
        if (p == 0) den[t] += qz + 1e-5f;
    }

    // out C[t][m] = Q @ Sp + A @ V
    f32x4 acco[4] = {};
    #pragma unroll
    for (int m4 = 0; m4 < 4; ++m4) {
        #pragma unroll
        for (int ck = 0; ck < 2; ++ck) {
            bf16x8 bs = *(const bf16x8*)&Ss[(m4 * 16 + fr) * LS + ck * 32 + fk];
            acco[m4] = __builtin_amdgcn_mfma_f32_16x16x32_bf16(aq[ck], bs, acco[m4], 0, 0, 0);
        }
    }
    bf16x8 aa[2];
    aa[0] = *(const bf16x8*)&As[(tbase + fr) * LS + fk];
    aa[1] = *(const bf16x8*)&As[(tbase + fr) * LS + 32 + fk];
    #pragma unroll
    for (int m4 = 0; m4 < 4; ++m4) {
        #pragma unroll
        for (int ck = 0; ck < 2; ++ck) {
            bf16x8 bv = *(const bf16x8*)&Vt[(m4 * 16 + fr) * LS + ck * 32 + fk];
            acco[m4] = __builtin_amdgcn_mfma_f32_16x16x32_bf16(aa[ck], bv, acco[m4], 0, 0, 0);
        }
    }
    __syncthreads();

    short* obase = attnb + bt0 * D + h * DH;
    #pragma unroll
    for (int r = 0; r < 4; ++r) {
        int tt = tbase + crow4 + r;
        float rv = 1.0f / den[tt];
        #pragma unroll
        for (int m4 = 0; m4 < 4; ++m4)
            obase[(size_t)tt * D + m4 * 16 + ccol] = to_bf16(acco[m4][r] * rv);
    }
}

// ---------------------------------------------------------------------------
// Proj GEMM, BK=32 + XCD-rectangle swizzle (unchanged).
// ---------------------------------------------------------------------------
__global__ __launch_bounds__(256) void gemm_proj64(const short* __restrict__ A,
                                                   const short* __restrict__ Bt,
                                                   const float* __restrict__ bias,
                                                   float* __restrict__ C) {
    constexpr int BK = 32, K = 1024, N = 1024;
    __shared__ short Als[64 * BK];    // 4 KB
    __shared__ short Bls[128 * BK];   // 8 KB

    const int bid   = blockIdx.x;
    const int xcd   = bid & 7;
    const int local = bid >> 3;            // 0..63
    const int cx = xcd & 3, ry = xcd >> 2; // 4 col-slabs x 2 row-slabs
    const int lx = local & 1, ly = local >> 1;
    const int bxx = cx * 2 + lx;           // 0..7 col-block
    const int byy = ry * 32 + ly;          // 0..63 row-block

    const int tid  = threadIdx.x;
    const int wave = tid >> 6;
    const int lane = tid & 63;
    const int row0 = byy * 64;
    const int col0 = bxx * 128;
    const int wn = wave * 32;

    f32x4 acc[4][2] = {};
    const int srow = lane >> 2;
    const int skk  = (lane & 3) * 8;
    const int fr = lane & 15;
    const int fk = (lane >> 4) * 8;

    for (int k0 = 0; k0 < K; k0 += BK) {
        __syncthreads();
        #pragma unroll
        for (int u = 0; u < 3; ++u) {
            int cc = wave * 3 + u;   // 0..11; 0..3 -> A chunks, 4..11 -> B chunks
            if (cc < 4) {
                int r = cc * 16 + srow;
                GLOAD_LDS16(A + (size_t)(row0 + r) * K + k0 + skk, &Als[cc * 512]);
            } else {
                int c2 = cc - 4;
                int r = c2 * 16 + srow;
                GLOAD_LDS16(Bt + (size_t)(col0 + r) * K + k0 + skk, &Bls[c2 * 512]);
            }
        }
        __syncthreads();

        bf16x8 af[4], bfr[2];
        #pragma unroll
        for (int i = 0; i < 4; ++i)
            af[i] = *(const bf16x8*)&Als[(i * 16 + fr) * BK + fk];
        #pragma unroll
        for (int j = 0; j < 2; ++j)
            bfr[j] = *(const bf16x8*)&Bls[(wn + j * 16 + fr) * BK + fk];
        #pragma unroll
        for (int mi = 0; mi < 4; ++mi)
            #pragma unroll
            for (int ni = 0; ni < 2; ++ni)
                acc[mi][ni] = __builtin_amdgcn_mfma_f32_16x16x32_bf16(af[mi], bfr[ni], acc[mi][ni], 0, 0, 0);
    }

    const int ccol  = lane & 15;
    const int crow4 = (lane >> 4) * 4;
    #pragma unroll
    for (int mi = 0; mi < 4; ++mi) {
        #pragma unroll
        for (int ni = 0; ni < 2; ++ni) {
            int col = col0 + wn + ni * 16 + ccol;
            float bv = bias[col];
            #pragma unroll
            for (int r = 0; r < 4; ++r) {
                int row = row0 + mi * 16 + crow4 + r;
                C[(size_t)row * N + col] = acc[mi][ni][r] + bv;
            }
        }
    }
}

// ---------------------------------------------------------------------------
extern "C" void kernel_launch(void* const* d_in, const int* in_sizes, int n_in,
                              void* d_out, int out_size, void* d_ws, size_t ws_size,
                              hipStream_t stream) {
    const float* x      = (const float*)d_in[0];
    const float* ln_g   = (const float*)d_in[1];
    const float* ln_b   = (const float*)d_in[2];
    const float* w_qkv  = (const float*)d_in[3];
    const float* b_qkv  = (const float*)d_in[4];
    const float* w_gate = (const float*)d_in[5];
    const float* b_gate = (const float*)d_in[6];
    const float* w_proj = (const float*)d_in[7];
    const float* b_proj = (const float*)d_in[8];
    float* out = (float*)d_out;

    short* xnb   = (short*)d_ws;                       // BT*D bf16 (8 MB)  [dead after GEMM]
    short* xb    = xnb + (size_t)BT * D;               // BT*D bf16 (8 MB)  [dead after GEMM]
    short* wTc   = xb + (size_t)BT * D;                // 4096*1024 bf16 (8 MB) [dead after GEMM]
    short* wTp   = wTc + (size_t)4096 * 1024;          // D*D bf16 (2 MB)
    short* qkvb  = wTp + (size_t)D * D;                // BT*3D bf16 (24 MB)
    short* sigb  = qkvb + (size_t)BT * 3 * D;          // BT*D bf16 (8 MB)
    short* attnb = sigb + (size_t)BT * D;              // BT*D bf16 (8 MB)
    float* zc    = (float*)(attnb + (size_t)BT * D);   // Bb*H*NC*DH fp32 (256 KB)
    float* gmean = zc + (size_t)Bb * H * NC * DH;      // BT fp32 (16 KB)
    float* Sc    = (float*)xnb;                        // Bb*H*NC*DH*DH fp32 (16 MB), aliases xnb+xb
    short* Spb   = wTc;                                // BT*D bf16 (8 MB), aliases wTc

    pre_kernel<<<1024 + 5120, 256, 0, stream>>>(x, ln_g, ln_b, w_qkv, w_gate, w_proj,
                                                xnb, xb, wTc, wTp, gmean);
    gemm_fused_qkvgate<<<256, 512, 0, stream>>>(
        xnb, xb, wTc, b_qkv, b_gate, qkvb, sigb, gmean);
    chunk_state_mfma<<<Bb * H * NC, 256, 0, stream>>>(qkvb, sigb, gmean, Sc, zc);
    chunk_prefix_kernel<<<Bb * H * 16, 256, 0, stream>>>(Sc, Spb, zc);
    chunk_attn_mfma<<<Bb * H * NC, 256, 0, stream>>>(qkvb, sigb, gmean, Spb, zc, attnb);
    gemm_proj64<<<512, 256, 0, stream>>>(attnb, wTp, b_proj, out);
}